// Round 6
// baseline (461.567 us; speedup 1.0000x reference)
//
#include <hip/hip_runtime.h>
#include <hip/hip_bf16.h>

// B=100000, C=64, R=128, H=32
// out[b,r,i,j] = sum_c w[b,r,c] * v[b,c,i]*v[b,c,j]
// w = relu(||v||_c @ W1 + b1) @ W2 + b2
//
// R6 = R5 structure (per-wave-private main loop, zero barriers after setup)
//  + FIX: W1T setup load covered only 512/2048 elements (R5's garbage source)
//  + all main-loop LDS accesses uint-typed (kill TBAA reordering risk)
//  + explicit lgkmcnt(0)+memory fences at stage boundaries
//  + cross-iteration w2t prefetch issued before the fence (lands during stage 2)

#define NB 16

typedef float f32x4 __attribute__((ext_vector_type(4)));
typedef __bf16 bf16x8 __attribute__((ext_vector_type(8)));
typedef unsigned int u32x4 __attribute__((ext_vector_type(4)));

static __device__ __forceinline__ unsigned short bf_bits(float f) {
  __hip_bfloat16 h = __float2bfloat16(f);
  return *reinterpret_cast<const unsigned short*>(&h);
}
static __device__ __forceinline__ unsigned int pack_bf2(float a, float b) {
  return (unsigned int)bf_bits(a) | ((unsigned int)bf_bits(b) << 16);
}
static __device__ __forceinline__ bf16x8 as_bf16x8(u32x4 u) {
  union { u32x4 u; bf16x8 b; } c; c.u = u; return c.b;
}

// ---- kernel 0: W2 [32][8192] fp32 -> W2T [8192][32] bf16 in workspace ----
__global__ void prep_w2t(const float* __restrict__ W2, unsigned short* __restrict__ w2t) {
  int rc = blockIdx.x * 256 + threadIdx.x;   // 0..8191
  unsigned int u[16];
#pragma unroll
  for (int kp = 0; kp < 16; ++kp) {
    float a = W2[(size_t)(2 * kp) * 8192 + rc];
    float b = W2[(size_t)(2 * kp + 1) * 8192 + rc];
    u[kp] = pack_bf2(a, b);
  }
  unsigned int* dst = reinterpret_cast<unsigned int*>(w2t + (size_t)rc * 32);
#pragma unroll
  for (int j = 0; j < 16; ++j) dst[j] = u[j];
}

// LDS map (bytes):
//  main loop: wave wid region [wid*9472, +9472): w bf16 [16b][296] ([4r][72]+8pad)
//             O staging overlays same region as uint [16b][36] (read-before-write order, verified)
//  setup overlays (dead before main loop, final barrier between):
//   [0,12288)      v_lds f32 [1024][3]
//   [12288,33024)  M_lds bf16 [16b][9s][72c] (b-stride 648)
//   [33024,41728)  W1T f32 [32][68]
//   [41728,46080)  s_lds f32 [16][68]
//   [46080,47104)  h_lds bf16 [16][32]
__global__ __launch_bounds__(256, 2)
void erl_main(const float* __restrict__ v, const float* __restrict__ W1,
              const float* __restrict__ b1, const float* __restrict__ b2,
              const unsigned short* __restrict__ w2t, float* __restrict__ out) {
  __shared__ __align__(16) char smem[47104];
  float* v_lds = reinterpret_cast<float*>(smem);
  unsigned short* M_lds = reinterpret_cast<unsigned short*>(smem + 12288);
  float* W1T = reinterpret_cast<float*>(smem + 33024);
  float* s_lds = reinterpret_cast<float*>(smem + 41728);
  unsigned short* h_lds = reinterpret_cast<unsigned short*>(smem + 46080);

  const int t = threadIdx.x;
  const int wid = t >> 6, lane = t & 63;
  const int x = lane >> 4, col = lane & 15;
  const int b0 = blockIdx.x * NB;

  // ---- (1) cooperative loads: v (12 KB) + W1 transpose (ALL 2048 elems) ----
  {
    const f32x4* src = reinterpret_cast<const f32x4*>(v + (size_t)b0 * 192);
    f32x4* dst = reinterpret_cast<f32x4*>(v_lds);
    dst[t] = src[t]; dst[t + 256] = src[t + 256]; dst[t + 512] = src[t + 512];
#pragma unroll
    for (int j = 0; j < 8; ++j) {
      int p = t + j * 256;                 // 0..2047; c = p>>5, k = p&31
      W1T[(p & 31) * 68 + (p >> 5)] = W1[p];
    }
  }
  __syncthreads();

  // ---- (2) norms -> s_lds, outer products -> M_lds (s = (i,j) row-major 3x3) ----
#pragma unroll
  for (int j = 0; j < 4; ++j) {
    int p = t + j * 256;
    int b = p >> 6, c = p & 63;
    float vx = v_lds[p * 3], vy = v_lds[p * 3 + 1], vz = v_lds[p * 3 + 2];
    s_lds[b * 68 + c] = sqrtf(vx * vx + vy * vy + vz * vz);
    unsigned short* mp = M_lds + b * 648 + c;
    unsigned short pxx = bf_bits(vx * vx), pxy = bf_bits(vx * vy), pxz = bf_bits(vx * vz);
    unsigned short pyy = bf_bits(vy * vy), pyz = bf_bits(vy * vz), pzz = bf_bits(vz * vz);
    mp[0] = pxx; mp[72] = pxy; mp[144] = pxz;
    mp[216] = pxy; mp[288] = pyy; mp[360] = pyz;
    mp[432] = pxz; mp[504] = pyz; mp[576] = pzz;
  }
  __syncthreads();

  // ---- (3) MLP: h[b][k] ----
  {
    int b = t >> 4, kk = t & 15;
    float a0 = b1[kk], a1 = b1[kk + 16];
#pragma unroll
    for (int c4 = 0; c4 < 16; ++c4) {
      f32x4 sv = *reinterpret_cast<const f32x4*>(s_lds + b * 68 + c4 * 4);
      f32x4 w0 = *reinterpret_cast<const f32x4*>(W1T + kk * 68 + c4 * 4);
      f32x4 w1 = *reinterpret_cast<const f32x4*>(W1T + (kk + 16) * 68 + c4 * 4);
#pragma unroll
      for (int u = 0; u < 4; ++u) {
        a0 = fmaf(sv[u], w0[u], a0);
        a1 = fmaf(sv[u], w1[u], a1);
      }
    }
    h_lds[b * 32 + kk] = bf_bits(fmaxf(a0, 0.f));
    h_lds[b * 32 + kk + 16] = bf_bits(fmaxf(a1, 0.f));
  }
  __syncthreads();

  // ---- (4) fragments to registers ----
  bf16x8 hfrag = *reinterpret_cast<const bf16x8*>(&h_lds[col * 32 + x * 8]);  // h[b=col][k=x*8+e]
  const int seff = (col < 9) ? col : 8;
  bf16x8 mfr[16][2];   // M[b][c=ch*32+x*8+e][s=seff]
#pragma unroll
  for (int b = 0; b < 16; ++b) {
#pragma unroll
    for (int ch = 0; ch < 2; ++ch)
      mfr[b][ch] = *reinterpret_cast<const bf16x8*>(&M_lds[b * 648 + seff * 72 + ch * 32 + x * 8]);
  }
  __syncthreads();   // last barrier: setup regions dead, main loop may overwrite

  // ---- main loop: barrier-free, wave-private (uint-typed LDS throughout) ----
  unsigned int* Wu = reinterpret_cast<unsigned int*>(smem + wid * 9472);  // [16b][148] dwords

  const int rbase0 = wid * 32;
  const unsigned short* ap = w2t + ((size_t)rbase0 * 64 + col) * 32 + x * 8;  // + tt*512; += 8192/it
  const float* b2p = b2 + rbase0 * 64 + x * 4;                                // + tt*16;  += 256/it
  const int wwr_u = col * 148 + x * 2;        // stage-1 write base (dwords): + (tt>>2)*36 + (tt&3)*8
  const int wrd_u = (col & 3) * 36 + x * 4;   // stage-2 read base (dwords):  + b*148 + ch*16
  unsigned int* outu = reinterpret_cast<unsigned int*>(out) + (size_t)b0 * 1152 + wid * 288 + lane;
  const bool ostore = (x == 0) && (col < 9);

  bf16x8 afA[4], afB[4];
#pragma unroll
  for (int j = 0; j < 4; ++j) afA[j] = *reinterpret_cast<const bf16x8*>(ap + j * 512);

  for (int it = 0; it < 8; ++it) {
    // ---- stage 1: w[4r][64c][16b] = W2T @ h^T + b2 : 16 tiles, groups of 4 ----
#pragma unroll
    for (int g = 0; g < 4; ++g) {
      if (g < 3) {
#pragma unroll
        for (int j = 0; j < 4; ++j)
          afB[j] = *reinterpret_cast<const bf16x8*>(ap + ((g + 1) * 4 + j) * 512);
      } else if (it < 7) {
        // prefetch next iteration's group 0 (in flight through stage 2 / flush)
#pragma unroll
        for (int j = 0; j < 4; ++j)
          afB[j] = *reinterpret_cast<const bf16x8*>(ap + 8192 + j * 512);
      }
#pragma unroll
      for (int j = 0; j < 4; ++j) {
        int tt = g * 4 + j;
        f32x4 acc = *reinterpret_cast<const f32x4*>(b2p + tt * 16);
        acc = __builtin_amdgcn_mfma_f32_16x16x32_bf16(afA[j], hfrag, acc, 0, 0, 0);
        // lane holds w[rc = tt*16 + x*4 + q][b=col]; rl = tt>>2, c = (tt&3)*16 + x*4 + q
        unsigned int* wp = &Wu[wwr_u + (tt >> 2) * 36 + (tt & 3) * 8];
        wp[0] = pack_bf2(acc[0], acc[1]);
        wp[1] = pack_bf2(acc[2], acc[3]);
      }
      afA[0] = afB[0]; afA[1] = afB[1]; afA[2] = afB[2]; afA[3] = afB[3];
    }
    ap += 8192; b2p += 256;

    // all stage-1 ds_writes visible to this wave's ds_reads; fence compiler reordering
    asm volatile("s_waitcnt lgkmcnt(0)" ::: "memory");

    // ---- stage 2: O[b][4r][9e] = W[r][c] @ M[c][e]; O -> staging (wave LDS overlay) ----
#pragma unroll
    for (int b = 0; b < 16; ++b) {
      bf16x8 a0 = as_bf16x8(*reinterpret_cast<const u32x4*>(&Wu[b * 148 + wrd_u]));
      bf16x8 a1 = as_bf16x8(*reinterpret_cast<const u32x4*>(&Wu[b * 148 + wrd_u + 16]));
      f32x4 o = {0.f, 0.f, 0.f, 0.f};
      o = __builtin_amdgcn_mfma_f32_16x16x32_bf16(a0, mfr[b][0], o, 0, 0, 0);
      o = __builtin_amdgcn_mfma_f32_16x16x32_bf16(a1, mfr[b][1], o, 0, 0, 0);
      if (ostore) {
        // rows r=q (x==0), cols e=col<9; overlay write [36b,36b+36) only touches
        // w-regions [148b',148b'+148) with b'<b (already consumed this iteration)
        unsigned int* od = &Wu[b * 36 + col];
        od[0]  = __float_as_uint(o[0]);
        od[9]  = __float_as_uint(o[1]);
        od[18] = __float_as_uint(o[2]);
        od[27] = __float_as_uint(o[3]);
      }
    }

    asm volatile("s_waitcnt lgkmcnt(0)" ::: "memory");

    // ---- flush: contiguous 144B stores per b ----
    if (lane < 36) {
#pragma unroll
      for (int b = 0; b < 16; ++b)
        outu[(size_t)b * 1152 + it * 36] = Wu[b * 36 + lane];
    }
  }
}

extern "C" void kernel_launch(void* const* d_in, const int* in_sizes, int n_in,
                              void* d_out, int out_size, void* d_ws, size_t ws_size,
                              hipStream_t stream) {
  const float* v  = (const float*)d_in[0];   // [100000,64,3]
  const float* W1 = (const float*)d_in[1];   // [64,32]
  const float* b1 = (const float*)d_in[2];   // [32]
  const float* W2 = (const float*)d_in[3];   // [32,8192]
  const float* b2 = (const float*)d_in[4];   // [8192]
  float* out = (float*)d_out;                // [100000,128,3,3]

  unsigned short* w2t = (unsigned short*)d_ws;  // [8192][32] bf16 = 512 KB

  prep_w2t<<<32, 256, 0, stream>>>(W2, w2t);
  erl_main<<<100000 / NB, 256, 0, stream>>>(v, W1, b1, b2, w2t, out);
}